// Round 6
// baseline (223.296 us; speedup 1.0000x reference)
//
#include <hip/hip_runtime.h>
#include <cstdint>
#include <cmath>

// Problem constants
#define B_    8
#define NHID_ 256
#define L_    2048
#define D_    512      // q/k/v channels (8 heads x 64)
#define DO_   2048     // output channels
#define QKVN  1536     // concat q|k|v

using u16    = unsigned short;
using short8 = __attribute__((ext_vector_type(8))) short;  // 8 bf16 (4 VGPRs)
using f32x4  = __attribute__((ext_vector_type(4))) float;  // 4 fp32 acc

typedef __attribute__((address_space(1))) void gv_t;
typedef __attribute__((address_space(3))) void lv_t;

__device__ inline void llds16(const void* g, void* l) {
  // async global->LDS, 16B/lane; LDS dest = wave-uniform base + lane*16
  __builtin_amdgcn_global_load_lds((const gv_t*)g, (lv_t*)l, 16, 0, 0);
}

__device__ inline u16 f32_to_bf16(float f) {
  unsigned u = __float_as_uint(f);
  u += 0x7fffu + ((u >> 16) & 1u);   // RNE (values finite)
  return (u16)(u >> 16);
}

__device__ inline void load8(const u16* p, float f[8]) {
  uint4 u = *reinterpret_cast<const uint4*>(p);
  f[0] = __uint_as_float(u.x << 16); f[1] = __uint_as_float(u.x & 0xffff0000u);
  f[2] = __uint_as_float(u.y << 16); f[3] = __uint_as_float(u.y & 0xffff0000u);
  f[4] = __uint_as_float(u.z << 16); f[5] = __uint_as_float(u.z & 0xffff0000u);
  f[6] = __uint_as_float(u.w << 16); f[7] = __uint_as_float(u.w & 0xffff0000u);
}

// ---------------------------------------------------------------------------
// prep (single launch): fp32 [R][C] -> bf16 [C][R] transposes for x and all
// weights, plus bias concat. 64x64 tiles, block (64,8).
// ---------------------------------------------------------------------------
template <int R, int C>
__device__ inline void t64(const float* __restrict__ src, u16* __restrict__ dst,
                           int id, float (*tile)[65]) {
  constexpr int TPR = C / 64;              // tiles along cols
  constexpr int PER = (R / 64) * TPR;      // tiles per z-slice
  int z = id / PER, rem = id % PER;
  int ry = rem / TPR, cx = rem % TPR;
  src += (size_t)z * R * C;
  dst += (size_t)z * R * C;
  int c0 = cx * 64, r0 = ry * 64;
  int tx = threadIdx.x, ty = threadIdx.y;
#pragma unroll
  for (int i = 0; i < 8; ++i)
    tile[ty + i * 8][tx] = src[(size_t)(r0 + ty + i * 8) * C + c0 + tx];
  __syncthreads();
#pragma unroll
  for (int i = 0; i < 8; ++i)
    dst[(size_t)(c0 + ty + i * 8) * R + r0 + tx] = f32_to_bf16(tile[tx][ty + i * 8]);
}

// block-id ranges (64x64 tiles)
#define PREP_WQ   1024     // x: 8 * (256/64) * (2048/64) = 1024 tiles
#define PREP_WK   1056     // Wq: (256/64)*(512/64) = 32 tiles
#define PREP_WV   1088
#define PREP_WO   1120
#define PREP_BIAS 1376     // Wo: (512/64)*(2048/64) = 256 tiles
#define PREP_NB   1379     // bias: 1536/512 = 3 blocks

__global__ void prep_all(const float* __restrict__ x,
                         const float* __restrict__ Wq, const float* __restrict__ Wk,
                         const float* __restrict__ Wv, const float* __restrict__ Wo,
                         const float* __restrict__ bq, const float* __restrict__ bk,
                         const float* __restrict__ bv,
                         u16* __restrict__ xb, u16* __restrict__ wqkvT,
                         u16* __restrict__ woT, float* __restrict__ bqkv) {
  __shared__ float tile[64][65];
  int bid = blockIdx.x;
  if (bid < PREP_WQ) {
    t64<NHID_, L_>(x, xb, bid, tile);
  } else if (bid < PREP_WK) {
    t64<NHID_, D_>(Wq, wqkvT, bid - PREP_WQ, tile);
  } else if (bid < PREP_WV) {
    t64<NHID_, D_>(Wk, wqkvT + 512 * NHID_, bid - PREP_WK, tile);
  } else if (bid < PREP_WO) {
    t64<NHID_, D_>(Wv, wqkvT + 1024 * NHID_, bid - PREP_WV, tile);
  } else if (bid < PREP_BIAS) {
    t64<D_, DO_>(Wo, woT, bid - PREP_WO, tile);
  } else {
    int d = (bid - PREP_BIAS) * 512 + threadIdx.y * 64 + threadIdx.x;
    float v = (d < 512) ? bq[d] : (d < 1024 ? bk[d - 512] : bv[d - 1024]);
    bqkv[d] = v;
  }
}

// ---------------------------------------------------------------------------
// Multi-tile m97-style A*B^T GEMM core. Same proven inner k-step (XOR-swizzled
// llds staging, 128x128 tile, BK=64, 4 waves, 4x4 16x16x32 MFMA) but each
// block processes T consecutive M-tiles at fixed n0:
//   - tile t's C-write overlaps the staging latency of tile t+1's first
//     K-chunk (epilogue was dead time in the 1-tile version),
//   - half the cold prologues; B-tile identical across the pair -> L2-hot,
//   - per-block life 2x -> phase desync across blocks.
// ---------------------------------------------------------------------------
#define BM 128
#define BN 128
#define BK 64

template <int K, int T, typename F>
__device__ inline void gemm_multi(const u16* __restrict__ gA, const u16* __restrict__ gB,
                                  int m0_base, int n0, u16* As, u16* Bs, F&& writeC) {
  const int tid = threadIdx.x;
  const int wave = tid >> 6, lane = tid & 63;
  const int wm = wave >> 1, wn = wave & 1;
  const int r8 = lane >> 3;                 // row within 8-row chunk
  const int kc = ((lane & 7) ^ r8) * 8;     // swizzled k element offset
  const int fr = lane & 15;                 // fragment row/col
  const int fx = fr & 7;                    // swizzle key for reads
  const int kq = lane >> 4;                 // fragment k-chunk 0..3

  auto stage = [&](int m0, int k0) {
#pragma unroll
    for (int t = 0; t < 4; ++t) {
      int chunk = wave * 4 + t;             // 16 chunks of 1KB per tile
      int row = chunk * 8 + r8;
      llds16(gA + (size_t)(m0 + row) * K + k0 + kc, (char*)As + chunk * 1024);
      llds16(gB + (size_t)(n0 + row) * K + k0 + kc, (char*)Bs + chunk * 1024);
    }
  };

  stage(m0_base, 0);                        // cold prologue (once per block)
  f32x4 acc[4][4];

  for (int t = 0; t < T; ++t) {
    const int m0 = m0_base + t * BM;
#pragma unroll
    for (int i = 0; i < 4; ++i)
#pragma unroll
      for (int j = 0; j < 4; ++j) acc[i][j] = f32x4{0.f, 0.f, 0.f, 0.f};

    for (int k0 = 0; k0 < K; k0 += BK) {
      __syncthreads();                      // drains staged chunk (vmcnt0+bar)
#pragma unroll
      for (int ks = 0; ks < 2; ++ks) {
        short8 a[4], b[4];
        const int slot = (((ks * 4 + kq) ^ fx)) * 8;
#pragma unroll
        for (int mt = 0; mt < 4; ++mt)
          a[mt] = *(const short8*)(As + (wm * 64 + mt * 16 + fr) * BK + slot);
#pragma unroll
        for (int nt = 0; nt < 4; ++nt)
          b[nt] = *(const short8*)(Bs + (wn * 64 + nt * 16 + fr) * BK + slot);
#pragma unroll
        for (int mt = 0; mt < 4; ++mt)
#pragma unroll
          for (int nt = 0; nt < 4; ++nt)
            acc[mt][nt] = __builtin_amdgcn_mfma_f32_16x16x32_bf16(a[mt], b[nt], acc[mt][nt], 0, 0, 0);
      }
      __syncthreads();                      // LDS reads done; safe to restage
      int nk = k0 + BK;
      if (nk < K) stage(m0, nk);            // next K-chunk of this tile
      else if (t + 1 < T) stage(m0 + BM, 0);// first K-chunk of next tile
    }
    // C-write overlaps the just-issued staging of tile t+1 (no LDS use here)
    writeC(m0, acc);
  }
}

// QKV GEMM: C[bl][d] = xb[bl][c] * WqkvT[d][c] + bqkv[d], store bf16.
// 768 blocks x 2 m-tiles (m-pair at fixed n0). Bijective XCD chunking: XCD k
// owns swz [96k,96k+96) -> m-rows [2048k,2048(k+1)) = batch k; per-XCD L2 set
// = 16 A-panels (1MB) + full B (0.8MB).
__global__ __launch_bounds__(256) void qkv_gemm(const u16* __restrict__ xb,
                                                const u16* __restrict__ wT,
                                                const float* __restrict__ bqkv,
                                                u16* __restrict__ qkv) {
  __shared__ __align__(16) u16 As[BM * BK];
  __shared__ __align__(16) u16 Bs[BN * BK];
  int id = blockIdx.x;                      // 768 blocks, %8==0
  int swz = (id & 7) * 96 + (id >> 3);      // bijective XCD chunking (T1)
  int n0 = (swz % 12) * BN;
  int m0_base = (swz / 12) * (2 * BM);
  gemm_multi<NHID_, 2>(xb, wT, m0_base, n0, As, Bs,
    [&](int m0, f32x4 (&acc)[4][4]) {
      const int lane = threadIdx.x & 63, wave = threadIdx.x >> 6;
      const int wm = wave >> 1, wn = wave & 1;
#pragma unroll
      for (int mt = 0; mt < 4; ++mt) {
        int row0 = m0 + wm * 64 + mt * 16 + (lane >> 4) * 4;
#pragma unroll
        for (int nt = 0; nt < 4; ++nt) {
          int col = n0 + wn * 64 + nt * 16 + (lane & 15);
          float bias = bqkv[col];
#pragma unroll
          for (int r = 0; r < 4; ++r)
            qkv[(size_t)(row0 + r) * QKVN + col] = f32_to_bf16(acc[mt][nt][r] + bias);
        }
      }
    });
}

// Out GEMM (swapped): C[j][l] = WoT[j][c] * att[b*L+l][c] + bo[j], fp32 store
// to out[b][j][l] -- coalesced along l. 1024 blocks x 2 j-panels at fixed
// (b, n0). XCD chunking: XCD k owns exactly b=k -> per-XCD L2 set = att[b]
// (2MB, written by attn on the same XCD) + woT (2MB).
__global__ __launch_bounds__(256) void out_gemm(const u16* __restrict__ woT,
                                                const u16* __restrict__ att,
                                                const float* __restrict__ bo,
                                                float* __restrict__ out) {
  __shared__ __align__(16) u16 As[BM * BK];
  __shared__ __align__(16) u16 Bs[BN * BK];
  int id = blockIdx.x;                      // 1024 blocks, %8==0
  int swz = (id & 7) * 128 + (id >> 3);     // bijective XCD chunking (T1)
  int b = swz >> 7;
  int rem = swz & 127;
  int n0 = (rem & 15) * BN;                 // l-tile
  int m0_base = (rem >> 4) * (2 * BM);      // j-pair base
  const u16* gB = att + (size_t)b * L_ * D_;
  float* outb = out + (size_t)b * DO_ * L_;
  gemm_multi<D_, 2>(woT, gB, m0_base, n0, As, Bs,
    [&](int m0, f32x4 (&acc)[4][4]) {
      const int lane = threadIdx.x & 63, wave = threadIdx.x >> 6;
      const int wm = wave >> 1, wn = wave & 1;
#pragma unroll
      for (int mt = 0; mt < 4; ++mt) {
        int row0 = m0 + wm * 64 + mt * 16 + (lane >> 4) * 4;
#pragma unroll
        for (int r = 0; r < 4; ++r) {
          float bias = bo[row0 + r];
#pragma unroll
          for (int nt = 0; nt < 4; ++nt) {
            int col = n0 + wn * 64 + nt * 16 + (lane & 15);
            outb[(size_t)(row0 + r) * L_ + col] = acc[mt][nt][r] + bias;
          }
        }
      }
    });
}

// ---------------------------------------------------------------------------
// Windowed attention, 2 rows per wave (round-5 verified). OOB window rows use
// k=v=0 and PARTICIPATE in softmax with score 0 (zero-pad semantics).
// 1024 blocks x 512 threads; XCD-chunked so XCD k handles batch b=k.
// ---------------------------------------------------------------------------
__global__ __launch_bounds__(512) void attn_kernel(const u16* __restrict__ qkv,
                                                   u16* __restrict__ att) {
  const int wave = threadIdx.x >> 6, lane = threadIdx.x & 63;
  int id = blockIdx.x;                      // 1024 blocks, %8==0
  int swz = (id & 7) * 128 + (id >> 3);     // bijective XCD chunking (T1)
  const int g = swz * 8 + wave;             // 8192 groups of 2 rows
  const int gr0 = g * 2;                    // first global row (even)
  const int l0 = gr0 & (L_ - 1);            // local l of row 0 (even)
  const int c0 = (lane >> 3) * 64 + (lane & 7) * 8;   // channel base, 8 per lane

  float q[2][8];
  load8(qkv + (size_t)gr0 * QKVN + c0, q[0]);
  load8(qkv + (size_t)(gr0 + 1) * QKVN + c0, q[1]);

  // k/v rows gr0-1 .. gr0+2  (j = 0..3)
  float kk[4][8], vv[4][8];
#pragma unroll
  for (int j = 0; j < 4; ++j) {
    bool valid = !(j == 0 && l0 == 0) && !(j == 3 && l0 == L_ - 2);
    if (valid) {
      const u16* base = qkv + (size_t)(gr0 - 1 + j) * QKVN;
      load8(base + 512 + c0, kk[j]);
      load8(base + 1024 + c0, vv[j]);
    } else {
#pragma unroll
      for (int t = 0; t < 8; ++t) { kk[j][t] = 0.f; vv[j][t] = 0.f; }
    }
  }

  // scores: row r window w uses k row j = r + w
  float s[2][3];
#pragma unroll
  for (int r = 0; r < 2; ++r)
#pragma unroll
    for (int w = 0; w < 3; ++w) {
      float a = 0.f;
#pragma unroll
      for (int t = 0; t < 8; ++t) a = fmaf(q[r][t], kk[r + w][t], a);
      s[r][w] = a;
    }
  // reduce over the 8 lanes of this head (butterfly; all lanes end with sum)
#pragma unroll
  for (int off = 1; off < 8; off <<= 1) {
#pragma unroll
    for (int r = 0; r < 2; ++r) {
      s[r][0] += __shfl_xor(s[r][0], off);
      s[r][1] += __shfl_xor(s[r][1], off);
      s[r][2] += __shfl_xor(s[r][2], off);
    }
  }

#pragma unroll
  for (int r = 0; r < 2; ++r) {
    float s0 = s[r][0] * 0.125f, s1 = s[r][1] * 0.125f, s2 = s[r][2] * 0.125f;
    float mx = fmaxf(s0, fmaxf(s1, s2));
    float e0 = __expf(s0 - mx), e1 = __expf(s1 - mx), e2 = __expf(s2 - mx);
    float inv = 1.f / (e0 + e1 + e2);
    float a0 = e0 * inv, a1 = e1 * inv, a2 = e2 * inv;

    u16 o16[8];
#pragma unroll
    for (int t = 0; t < 8; ++t) {
      float o = a0 * vv[r][t] + a1 * vv[r + 1][t] + a2 * vv[r + 2][t];
      o16[t] = f32_to_bf16(o);
    }
    uint4 pk;
    pk.x = (unsigned)o16[0] | ((unsigned)o16[1] << 16);
    pk.y = (unsigned)o16[2] | ((unsigned)o16[3] << 16);
    pk.z = (unsigned)o16[4] | ((unsigned)o16[5] << 16);
    pk.w = (unsigned)o16[6] | ((unsigned)o16[7] << 16);
    *reinterpret_cast<uint4*>(att + (size_t)(gr0 + r) * D_ + c0) = pk;
  }
}

// ---------------------------------------------------------------------------
extern "C" void kernel_launch(void* const* d_in, const int* in_sizes, int n_in,
                              void* d_out, int out_size, void* d_ws, size_t ws_size,
                              hipStream_t stream) {
  const float* x  = (const float*)d_in[0];
  const float* Wq = (const float*)d_in[1];
  const float* bq = (const float*)d_in[2];
  const float* Wk = (const float*)d_in[3];
  const float* bk = (const float*)d_in[4];
  const float* Wv = (const float*)d_in[5];
  const float* bv = (const float*)d_in[6];
  const float* Wo = (const float*)d_in[7];
  const float* bo = (const float*)d_in[8];
  float* out = (float*)d_out;

  char* ws = (char*)d_ws;
  // workspace layout (bytes)
  u16*   xb    = (u16*)(ws + 0);            //  16384x256  bf16  (8388608)
  u16*   wqkvT = (u16*)(ws + 8388608);      //  1536x256   bf16  (786432)
  u16*   woT   = (u16*)(ws + 9175040);      //  2048x512   bf16  (2097152)
  float* bqkv  = (float*)(ws + 11272192);   //  1536       f32   (6144)
  u16*   qkv   = (u16*)(ws + 11278336);     //  16384x1536 bf16  (50331648)
  u16*   att   = (u16*)(ws + 61609984);     //  16384x512  bf16  (16777216)
  // total ~78.4 MB

  // all transposes + bias in ONE launch (64x64 tiles, block (64,8))
  prep_all<<<PREP_NB, dim3(64, 8), 0, stream>>>(x, Wq, Wk, Wv, Wo, bq, bk, bv,
                                                xb, wqkvT, woT, bqkv);

  // QKV projection: [16384 x 1536] = xb [16384x256] * wqkvT^T  (2 m-tiles/block)
  qkv_gemm<<<768, 256, 0, stream>>>(xb, wqkvT, bqkv, qkv);

  // windowed softmax attention -> att [16384x512] bf16 (2 rows/wave)
  attn_kernel<<<(B_ * L_) / 16, 512, 0, stream>>>(qkv, att);

  // output projection, transposed store: out[b][j][l]  (2 j-panels/block)
  out_gemm<<<1024, 256, 0, stream>>>(woT, att, bo, out);
}

// Round 7
// 222.937 us; speedup vs baseline: 1.0016x; 1.0016x over previous
//
#include <hip/hip_runtime.h>
#include <cstdint>
#include <cmath>

// Problem constants
#define B_    8
#define NHID_ 256
#define L_    2048
#define D_    512      // q/k/v channels (8 heads x 64)
#define DO_   2048     // output channels
#define QKVN  1536     // concat q|k|v

using u16    = unsigned short;
using short8 = __attribute__((ext_vector_type(8))) short;  // 8 bf16 (4 VGPRs)
using f32x4  = __attribute__((ext_vector_type(4))) float;  // 4 fp32 acc

typedef __attribute__((address_space(1))) void gv_t;
typedef __attribute__((address_space(3))) void lv_t;

__device__ inline void llds16(const void* g, void* l) {
  // async global->LDS, 16B/lane; LDS dest = wave-uniform base + lane*16
  __builtin_amdgcn_global_load_lds((const gv_t*)g, (lv_t*)l, 16, 0, 0);
}

__device__ inline u16 f32_to_bf16(float f) {
  unsigned u = __float_as_uint(f);
  u += 0x7fffu + ((u >> 16) & 1u);   // RNE (values finite)
  return (u16)(u >> 16);
}

__device__ inline void load8(const u16* p, float f[8]) {
  uint4 u = *reinterpret_cast<const uint4*>(p);
  f[0] = __uint_as_float(u.x << 16); f[1] = __uint_as_float(u.x & 0xffff0000u);
  f[2] = __uint_as_float(u.y << 16); f[3] = __uint_as_float(u.y & 0xffff0000u);
  f[4] = __uint_as_float(u.z << 16); f[5] = __uint_as_float(u.z & 0xffff0000u);
  f[6] = __uint_as_float(u.w << 16); f[7] = __uint_as_float(u.w & 0xffff0000u);
}

// ---------------------------------------------------------------------------
// prep (single launch): fp32 [R][C] -> bf16 [C][R] transposes for x and all
// weights, plus bias concat. 64x64 tiles, block (64,8).
// ---------------------------------------------------------------------------
template <int R, int C>
__device__ inline void t64(const float* __restrict__ src, u16* __restrict__ dst,
                           int id, float (*tile)[65]) {
  constexpr int TPR = C / 64;              // tiles along cols
  constexpr int PER = (R / 64) * TPR;      // tiles per z-slice
  int z = id / PER, rem = id % PER;
  int ry = rem / TPR, cx = rem % TPR;
  src += (size_t)z * R * C;
  dst += (size_t)z * R * C;
  int c0 = cx * 64, r0 = ry * 64;
  int tx = threadIdx.x, ty = threadIdx.y;
#pragma unroll
  for (int i = 0; i < 8; ++i)
    tile[ty + i * 8][tx] = src[(size_t)(r0 + ty + i * 8) * C + c0 + tx];
  __syncthreads();
#pragma unroll
  for (int i = 0; i < 8; ++i)
    dst[(size_t)(c0 + ty + i * 8) * R + r0 + tx] = f32_to_bf16(tile[tx][ty + i * 8]);
}

// block-id ranges (64x64 tiles)
#define PREP_WQ   1024     // x: 8 * (256/64) * (2048/64) = 1024 tiles
#define PREP_WK   1056     // Wq: (256/64)*(512/64) = 32 tiles
#define PREP_WV   1088
#define PREP_WO   1120
#define PREP_BIAS 1376     // Wo: (512/64)*(2048/64) = 256 tiles
#define PREP_NB   1379     // bias: 1536/512 = 3 blocks

__global__ void prep_all(const float* __restrict__ x,
                         const float* __restrict__ Wq, const float* __restrict__ Wk,
                         const float* __restrict__ Wv, const float* __restrict__ Wo,
                         const float* __restrict__ bq, const float* __restrict__ bk,
                         const float* __restrict__ bv,
                         u16* __restrict__ xb, u16* __restrict__ wqkvT,
                         u16* __restrict__ woT, float* __restrict__ bqkv) {
  __shared__ float tile[64][65];
  int bid = blockIdx.x;
  if (bid < PREP_WQ) {
    t64<NHID_, L_>(x, xb, bid, tile);
  } else if (bid < PREP_WK) {
    t64<NHID_, D_>(Wq, wqkvT, bid - PREP_WQ, tile);
  } else if (bid < PREP_WV) {
    t64<NHID_, D_>(Wk, wqkvT + 512 * NHID_, bid - PREP_WK, tile);
  } else if (bid < PREP_WO) {
    t64<NHID_, D_>(Wv, wqkvT + 1024 * NHID_, bid - PREP_WV, tile);
  } else if (bid < PREP_BIAS) {
    t64<D_, DO_>(Wo, woT, bid - PREP_WO, tile);
  } else {
    int d = (bid - PREP_BIAS) * 512 + threadIdx.y * 64 + threadIdx.x;
    float v = (d < 512) ? bq[d] : (d < 1024 ? bk[d - 512] : bv[d - 1024]);
    bqkv[d] = v;
  }
}

// ---------------------------------------------------------------------------
// m97-style A*B^T GEMM core with XOR-swizzled LDS staging (round-0/5 proven).
// A [M][K], B [N][K] bf16 row-major (K contiguous), 128x128 tile, BK=64,
// 256 threads = 4 waves (2x2), 4x4 16x16x32 MFMA per wave. 32 KiB LDS.
// Cross-block overlap is the operative latency-hiding resource (R2/R6
// evidence): occupancy is pushed to 4 blocks/CU via __launch_bounds__(256,4)
// on the callers (VGPR cap 128; est. need ~115; LDS allows 5).
// ---------------------------------------------------------------------------
#define BM 128
#define BN 128
#define BK 64

template <int K>
__device__ inline void gemm_tile(const u16* __restrict__ gA, const u16* __restrict__ gB,
                                 int m0, int n0, u16* As, u16* Bs, f32x4 (&acc)[4][4]) {
  const int tid = threadIdx.x;
  const int wave = tid >> 6, lane = tid & 63;
  const int wm = wave >> 1, wn = wave & 1;
  const int r8 = lane >> 3;                 // row within 8-row chunk
  const int kc = ((lane & 7) ^ r8) * 8;     // swizzled k element offset
  const int fr = lane & 15;                 // fragment row/col
  const int fx = fr & 7;                    // swizzle key for reads
  const int kq = lane >> 4;                 // fragment k-chunk 0..3

  auto stage = [&](int k0) {
#pragma unroll
    for (int t = 0; t < 4; ++t) {
      int chunk = wave * 4 + t;             // 16 chunks of 1KB per tile
      int row = chunk * 8 + r8;
      llds16(gA + (size_t)(m0 + row) * K + k0 + kc, (char*)As + chunk * 1024);
      llds16(gB + (size_t)(n0 + row) * K + k0 + kc, (char*)Bs + chunk * 1024);
    }
  };

  stage(0);                                 // overlap first staging with init
#pragma unroll
  for (int i = 0; i < 4; ++i)
#pragma unroll
    for (int j = 0; j < 4; ++j) acc[i][j] = f32x4{0.f, 0.f, 0.f, 0.f};

  for (int k0 = 0;;) {
    __syncthreads();                        // drains staging (vmcnt0 + barrier)
#pragma unroll
    for (int ks = 0; ks < 2; ++ks) {
      short8 a[4], b[4];
      const int slot = (((ks * 4 + kq) ^ fx)) * 8;
#pragma unroll
      for (int mt = 0; mt < 4; ++mt)
        a[mt] = *(const short8*)(As + (wm * 64 + mt * 16 + fr) * BK + slot);
#pragma unroll
      for (int nt = 0; nt < 4; ++nt)
        b[nt] = *(const short8*)(Bs + (wn * 64 + nt * 16 + fr) * BK + slot);
#pragma unroll
      for (int mt = 0; mt < 4; ++mt)
#pragma unroll
        for (int nt = 0; nt < 4; ++nt)
          acc[mt][nt] = __builtin_amdgcn_mfma_f32_16x16x32_bf16(a[mt], b[nt], acc[mt][nt], 0, 0, 0);
    }
    k0 += BK;
    if (k0 >= K) break;
    __syncthreads();                        // LDS reads done; safe to restage
    stage(k0);
  }
}

// QKV GEMM: C[bl][d] = xb[bl][c] * WqkvT[d][c] + bqkv[d], store bf16.
// 1D grid 1536 with bijective XCD chunking: XCD k owns m-panels [16k,16k+16)
// (= batch b=k rows) x all 12 n-tiles -> per-XCD L2 set = 16x64KB A-panels +
// full B (0.8MB) ~ 1.8 MB < 4 MB.
__global__ __launch_bounds__(256, 4) void qkv_gemm(const u16* __restrict__ xb,
                                                   const u16* __restrict__ wT,
                                                   const float* __restrict__ bqkv,
                                                   u16* __restrict__ qkv) {
  __shared__ __align__(16) u16 As[BM * BK];
  __shared__ __align__(16) u16 Bs[BN * BK];
  int id = blockIdx.x;                      // 1536 blocks, %8==0
  int swz = (id & 7) * 192 + (id >> 3);     // bijective XCD chunking (T1)
  int n0 = (swz % 12) * BN;
  int m0 = (swz / 12) * BM;
  f32x4 acc[4][4];
  gemm_tile<NHID_>(xb, wT, m0, n0, As, Bs, acc);
  const int lane = threadIdx.x & 63, wave = threadIdx.x >> 6;
  const int wm = wave >> 1, wn = wave & 1;
#pragma unroll
  for (int mt = 0; mt < 4; ++mt) {
    int row0 = m0 + wm * 64 + mt * 16 + (lane >> 4) * 4;
#pragma unroll
    for (int nt = 0; nt < 4; ++nt) {
      int col = n0 + wn * 64 + nt * 16 + (lane & 15);
      float bias = bqkv[col];
#pragma unroll
      for (int r = 0; r < 4; ++r)
        qkv[(size_t)(row0 + r) * QKVN + col] = f32_to_bf16(acc[mt][nt][r] + bias);
    }
  }
}

// Out GEMM (swapped): C[j][l] = WoT[j][c] * att[b*L+l][c] + bo[j], fp32 store
// to out[b][j][l] -- coalesced along l (MFMA C col = lane&15).
// 1D grid 2048 with XCD chunking: XCD k owns exactly b=k (256 blocks) ->
// per-XCD L2 set = att[b] (2MB, written by attn on the same XCD) + woT (2MB).
__global__ __launch_bounds__(256, 4) void out_gemm(const u16* __restrict__ woT,
                                                   const u16* __restrict__ att,
                                                   const float* __restrict__ bo,
                                                   float* __restrict__ out) {
  __shared__ __align__(16) u16 As[BM * BK];
  __shared__ __align__(16) u16 Bs[BN * BK];
  int id = blockIdx.x;                      // 2048 blocks, %8==0
  int swz = (id & 7) * 256 + (id >> 3);     // bijective XCD chunking (T1)
  int b = swz >> 8;
  int rem = swz & 255;
  int m0 = (rem >> 4) * BM;                 // j-panel
  int n0 = (rem & 15) * BN;                 // l-tile
  const u16* gB = att + (size_t)b * L_ * D_;
  f32x4 acc[4][4];
  gemm_tile<D_>(woT, gB, m0, n0, As, Bs, acc);
  const int lane = threadIdx.x & 63, wave = threadIdx.x >> 6;
  const int wm = wave >> 1, wn = wave & 1;
  float* outb = out + (size_t)b * DO_ * L_;
#pragma unroll
  for (int mt = 0; mt < 4; ++mt) {
    int row0 = m0 + wm * 64 + mt * 16 + (lane >> 4) * 4;
#pragma unroll
    for (int r = 0; r < 4; ++r) {
      float bias = bo[row0 + r];
#pragma unroll
      for (int nt = 0; nt < 4; ++nt) {
        int col = n0 + wn * 64 + nt * 16 + (lane & 15);
        outb[(size_t)(row0 + r) * L_ + col] = acc[mt][nt][r] + bias;
      }
    }
  }
}

// ---------------------------------------------------------------------------
// Windowed attention, 2 rows per wave (round-5 verified). OOB window rows use
// k=v=0 and PARTICIPATE in softmax with score 0 (zero-pad semantics).
// 1024 blocks x 512 threads; XCD-chunked so XCD k handles batch b=k.
// ---------------------------------------------------------------------------
__global__ __launch_bounds__(512) void attn_kernel(const u16* __restrict__ qkv,
                                                   u16* __restrict__ att) {
  const int wave = threadIdx.x >> 6, lane = threadIdx.x & 63;
  int id = blockIdx.x;                      // 1024 blocks, %8==0
  int swz = (id & 7) * 128 + (id >> 3);     // bijective XCD chunking (T1)
  const int g = swz * 8 + wave;             // 8192 groups of 2 rows
  const int gr0 = g * 2;                    // first global row (even)
  const int l0 = gr0 & (L_ - 1);            // local l of row 0 (even)
  const int c0 = (lane >> 3) * 64 + (lane & 7) * 8;   // channel base, 8 per lane

  float q[2][8];
  load8(qkv + (size_t)gr0 * QKVN + c0, q[0]);
  load8(qkv + (size_t)(gr0 + 1) * QKVN + c0, q[1]);

  // k/v rows gr0-1 .. gr0+2  (j = 0..3)
  float kk[4][8], vv[4][8];
#pragma unroll
  for (int j = 0; j < 4; ++j) {
    bool valid = !(j == 0 && l0 == 0) && !(j == 3 && l0 == L_ - 2);
    if (valid) {
      const u16* base = qkv + (size_t)(gr0 - 1 + j) * QKVN;
      load8(base + 512 + c0, kk[j]);
      load8(base + 1024 + c0, vv[j]);
    } else {
#pragma unroll
      for (int t = 0; t < 8; ++t) { kk[j][t] = 0.f; vv[j][t] = 0.f; }
    }
  }

  // scores: row r window w uses k row j = r + w
  float s[2][3];
#pragma unroll
  for (int r = 0; r < 2; ++r)
#pragma unroll
    for (int w = 0; w < 3; ++w) {
      float a = 0.f;
#pragma unroll
      for (int t = 0; t < 8; ++t) a = fmaf(q[r][t], kk[r + w][t], a);
      s[r][w] = a;
    }
  // reduce over the 8 lanes of this head (butterfly; all lanes end with sum)
#pragma unroll
  for (int off = 1; off < 8; off <<= 1) {
#pragma unroll
    for (int r = 0; r < 2; ++r) {
      s[r][0] += __shfl_xor(s[r][0], off);
      s[r][1] += __shfl_xor(s[r][1], off);
      s[r][2] += __shfl_xor(s[r][2], off);
    }
  }

#pragma unroll
  for (int r = 0; r < 2; ++r) {
    float s0 = s[r][0] * 0.125f, s1 = s[r][1] * 0.125f, s2 = s[r][2] * 0.125f;
    float mx = fmaxf(s0, fmaxf(s1, s2));
    float e0 = __expf(s0 - mx), e1 = __expf(s1 - mx), e2 = __expf(s2 - mx);
    float inv = 1.f / (e0 + e1 + e2);
    float a0 = e0 * inv, a1 = e1 * inv, a2 = e2 * inv;

    u16 o16[8];
#pragma unroll
    for (int t = 0; t < 8; ++t) {
      float o = a0 * vv[r][t] + a1 * vv[r + 1][t] + a2 * vv[r + 2][t];
      o16[t] = f32_to_bf16(o);
    }
    uint4 pk;
    pk.x = (unsigned)o16[0] | ((unsigned)o16[1] << 16);
    pk.y = (unsigned)o16[2] | ((unsigned)o16[3] << 16);
    pk.z = (unsigned)o16[4] | ((unsigned)o16[5] << 16);
    pk.w = (unsigned)o16[6] | ((unsigned)o16[7] << 16);
    *reinterpret_cast<uint4*>(att + (size_t)(gr0 + r) * D_ + c0) = pk;
  }
}

// ---------------------------------------------------------------------------
extern "C" void kernel_launch(void* const* d_in, const int* in_sizes, int n_in,
                              void* d_out, int out_size, void* d_ws, size_t ws_size,
                              hipStream_t stream) {
  const float* x  = (const float*)d_in[0];
  const float* Wq = (const float*)d_in[1];
  const float* bq = (const float*)d_in[2];
  const float* Wk = (const float*)d_in[3];
  const float* bk = (const float*)d_in[4];
  const float* Wv = (const float*)d_in[5];
  const float* bv = (const float*)d_in[6];
  const float* Wo = (const float*)d_in[7];
  const float* bo = (const float*)d_in[8];
  float* out = (float*)d_out;

  char* ws = (char*)d_ws;
  // workspace layout (bytes)
  u16*   xb    = (u16*)(ws + 0);            //  16384x256  bf16  (8388608)
  u16*   wqkvT = (u16*)(ws + 8388608);      //  1536x256   bf16  (786432)
  u16*   woT   = (u16*)(ws + 9175040);      //  2048x512   bf16  (2097152)
  float* bqkv  = (float*)(ws + 11272192);   //  1536       f32   (6144)
  u16*   qkv   = (u16*)(ws + 11278336);     //  16384x1536 bf16  (50331648)
  u16*   att   = (u16*)(ws + 61609984);     //  16384x512  bf16  (16777216)
  // total ~78.4 MB

  // all transposes + bias in ONE launch (64x64 tiles, block (64,8))
  prep_all<<<PREP_NB, dim3(64, 8), 0, stream>>>(x, Wq, Wk, Wv, Wo, bq, bk, bv,
                                                xb, wqkvT, woT, bqkv);

  // QKV projection: [16384 x 1536] = xb [16384x256] * wqkvT^T
  qkv_gemm<<<(QKVN / BN) * ((B_ * L_) / BM), 256, 0, stream>>>(xb, wqkvT, bqkv, qkv);

  // windowed softmax attention -> att [16384x512] bf16 (2 rows/wave)
  attn_kernel<<<(B_ * L_) / 16, 512, 0, stream>>>(qkv, att);

  // output projection, transposed store: out[b][j][l]
  out_gemm<<<(L_ / BN) * (DO_ / BM) * B_, 256, 0, stream>>>(woT, att, bo, out);
}

// Round 8
// 219.501 us; speedup vs baseline: 1.0173x; 1.0157x over previous
//
#include <hip/hip_runtime.h>
#include <cstdint>
#include <cmath>

// Problem constants
#define B_    8
#define NHID_ 256
#define L_    2048
#define D_    512      // q/k/v channels (8 heads x 64)
#define DO_   2048     // output channels
#define QKVN  1536     // concat q|k|v

using u16    = unsigned short;
using short8 = __attribute__((ext_vector_type(8))) short;  // 8 bf16 (4 VGPRs)
using f32x4  = __attribute__((ext_vector_type(4))) float;  // 4 fp32 acc

typedef __attribute__((address_space(1))) void gv_t;
typedef __attribute__((address_space(3))) void lv_t;

__device__ inline void llds16(const void* g, void* l) {
  // async global->LDS, 16B/lane; LDS dest = wave-uniform base + lane*16
  __builtin_amdgcn_global_load_lds((const gv_t*)g, (lv_t*)l, 16, 0, 0);
}

__device__ inline u16 f32_to_bf16(float f) {
  unsigned u = __float_as_uint(f);
  u += 0x7fffu + ((u >> 16) & 1u);   // RNE (values finite)
  return (u16)(u >> 16);
}

__device__ inline void load8(const u16* p, float f[8]) {
  uint4 u = *reinterpret_cast<const uint4*>(p);
  f[0] = __uint_as_float(u.x << 16); f[1] = __uint_as_float(u.x & 0xffff0000u);
  f[2] = __uint_as_float(u.y << 16); f[3] = __uint_as_float(u.y & 0xffff0000u);
  f[4] = __uint_as_float(u.z << 16); f[5] = __uint_as_float(u.z & 0xffff0000u);
  f[6] = __uint_as_float(u.w << 16); f[7] = __uint_as_float(u.w & 0xffff0000u);
}

// ---------------------------------------------------------------------------
// prep (single launch): fp32 [R][C] -> bf16 [C][R] transposes for x and all
// weights, plus bias concat. 64x64 tiles, block (64,8).
// ---------------------------------------------------------------------------
template <int R, int C>
__device__ inline void t64(const float* __restrict__ src, u16* __restrict__ dst,
                           int id, float (*tile)[65]) {
  constexpr int TPR = C / 64;              // tiles along cols
  constexpr int PER = (R / 64) * TPR;      // tiles per z-slice
  int z = id / PER, rem = id % PER;
  int ry = rem / TPR, cx = rem % TPR;
  src += (size_t)z * R * C;
  dst += (size_t)z * R * C;
  int c0 = cx * 64, r0 = ry * 64;
  int tx = threadIdx.x, ty = threadIdx.y;
#pragma unroll
  for (int i = 0; i < 8; ++i)
    tile[ty + i * 8][tx] = src[(size_t)(r0 + ty + i * 8) * C + c0 + tx];
  __syncthreads();
#pragma unroll
  for (int i = 0; i < 8; ++i)
    dst[(size_t)(c0 + ty + i * 8) * R + r0 + tx] = f32_to_bf16(tile[tx][ty + i * 8]);
}

// block-id ranges (64x64 tiles)
#define PREP_WQ   1024     // x: 8 * (256/64) * (2048/64) = 1024 tiles
#define PREP_WK   1056     // Wq: (256/64)*(512/64) = 32 tiles
#define PREP_WV   1088
#define PREP_WO   1120
#define PREP_BIAS 1376     // Wo: (512/64)*(2048/64) = 256 tiles
#define PREP_NB   1379     // bias: 1536/512 = 3 blocks

__global__ void prep_all(const float* __restrict__ x,
                         const float* __restrict__ Wq, const float* __restrict__ Wk,
                         const float* __restrict__ Wv, const float* __restrict__ Wo,
                         const float* __restrict__ bq, const float* __restrict__ bk,
                         const float* __restrict__ bv,
                         u16* __restrict__ xb, u16* __restrict__ wqkvT,
                         u16* __restrict__ woT, float* __restrict__ bqkv) {
  __shared__ float tile[64][65];
  int bid = blockIdx.x;
  if (bid < PREP_WQ) {
    t64<NHID_, L_>(x, xb, bid, tile);
  } else if (bid < PREP_WK) {
    t64<NHID_, D_>(Wq, wqkvT, bid - PREP_WQ, tile);
  } else if (bid < PREP_WV) {
    t64<NHID_, D_>(Wk, wqkvT + 512 * NHID_, bid - PREP_WK, tile);
  } else if (bid < PREP_WO) {
    t64<NHID_, D_>(Wv, wqkvT + 1024 * NHID_, bid - PREP_WV, tile);
  } else if (bid < PREP_BIAS) {
    t64<D_, DO_>(Wo, woT, bid - PREP_WO, tile);
  } else {
    int d = (bid - PREP_BIAS) * 512 + threadIdx.y * 64 + threadIdx.x;
    float v = (d < 512) ? bq[d] : (d < 1024 ? bk[d - 512] : bv[d - 1024]);
    bqkv[d] = v;
  }
}

// ---------------------------------------------------------------------------
// m97-style A*B^T GEMM core with XOR-swizzled LDS staging (round-0/5 proven).
// A [M][K], B [N][K] bf16 row-major (K contiguous), 128x128 tile, BK=64,
// 256 threads = 4 waves (2x2), 4x4 16x16x32 MFMA per wave. 32 KiB LDS ->
// ~3 blocks/CU at the compiler's natural ~150 VGPR; cross-block staggered
// phases hide the vmcnt(0)+barrier drain (m114). Forcing 4 blocks/CU via
// launch_bounds(256,4) regressed (R7: VGPR cap 128 -> spills); leave free.
// ---------------------------------------------------------------------------
#define BM 128
#define BN 128
#define BK 64

template <int K>
__device__ inline void gemm_tile(const u16* __restrict__ gA, const u16* __restrict__ gB,
                                 int m0, int n0, u16* As, u16* Bs, f32x4 (&acc)[4][4]) {
  const int tid = threadIdx.x;
  const int wave = tid >> 6, lane = tid & 63;
  const int wm = wave >> 1, wn = wave & 1;
  const int r8 = lane >> 3;                 // row within 8-row chunk
  const int kc = ((lane & 7) ^ r8) * 8;     // swizzled k element offset
  const int fr = lane & 15;                 // fragment row/col
  const int fx = fr & 7;                    // swizzle key for reads
  const int kq = lane >> 4;                 // fragment k-chunk 0..3

  auto stage = [&](int k0) {
#pragma unroll
    for (int t = 0; t < 4; ++t) {
      int chunk = wave * 4 + t;             // 16 chunks of 1KB per tile
      int row = chunk * 8 + r8;
      llds16(gA + (size_t)(m0 + row) * K + k0 + kc, (char*)As + chunk * 1024);
      llds16(gB + (size_t)(n0 + row) * K + k0 + kc, (char*)Bs + chunk * 1024);
    }
  };

  stage(0);                                 // overlap first staging with init
#pragma unroll
  for (int i = 0; i < 4; ++i)
#pragma unroll
    for (int j = 0; j < 4; ++j) acc[i][j] = f32x4{0.f, 0.f, 0.f, 0.f};

  for (int k0 = 0;;) {
    __syncthreads();                        // drains staging (vmcnt0 + barrier)
#pragma unroll
    for (int ks = 0; ks < 2; ++ks) {
      short8 a[4], b[4];
      const int slot = (((ks * 4 + kq) ^ fx)) * 8;
#pragma unroll
      for (int mt = 0; mt < 4; ++mt)
        a[mt] = *(const short8*)(As + (wm * 64 + mt * 16 + fr) * BK + slot);
#pragma unroll
      for (int nt = 0; nt < 4; ++nt)
        b[nt] = *(const short8*)(Bs + (wn * 64 + nt * 16 + fr) * BK + slot);
#pragma unroll
      for (int mt = 0; mt < 4; ++mt)
#pragma unroll
        for (int nt = 0; nt < 4; ++nt)
          acc[mt][nt] = __builtin_amdgcn_mfma_f32_16x16x32_bf16(a[mt], b[nt], acc[mt][nt], 0, 0, 0);
    }
    k0 += BK;
    if (k0 >= K) break;
    __syncthreads();                        // LDS reads done; safe to restage
    stage(k0);
  }
}

// QKV GEMM: C[bl][d] = xb[bl][c] * WqkvT[d][c] + bqkv[d], store bf16.
// 1D grid 1536 with bijective XCD chunking: XCD k owns m-panels [16k,16k+16)
// (= batch b=k rows) x all 12 n-tiles -> per-XCD L2 set = 16x64KB A-panels +
// full B (0.8MB) ~ 1.8 MB < 4 MB.
__global__ __launch_bounds__(256) void qkv_gemm(const u16* __restrict__ xb,
                                                const u16* __restrict__ wT,
                                                const float* __restrict__ bqkv,
                                                u16* __restrict__ qkv) {
  __shared__ __align__(16) u16 As[BM * BK];
  __shared__ __align__(16) u16 Bs[BN * BK];
  int id = blockIdx.x;                      // 1536 blocks, %8==0
  int swz = (id & 7) * 192 + (id >> 3);     // bijective XCD chunking (T1)
  int n0 = (swz % 12) * BN;
  int m0 = (swz / 12) * BM;
  f32x4 acc[4][4];
  gemm_tile<NHID_>(xb, wT, m0, n0, As, Bs, acc);
  const int lane = threadIdx.x & 63, wave = threadIdx.x >> 6;
  const int wm = wave >> 1, wn = wave & 1;
#pragma unroll
  for (int mt = 0; mt < 4; ++mt) {
    int row0 = m0 + wm * 64 + mt * 16 + (lane >> 4) * 4;
#pragma unroll
    for (int nt = 0; nt < 4; ++nt) {
      int col = n0 + wn * 64 + nt * 16 + (lane & 15);
      float bias = bqkv[col];
#pragma unroll
      for (int r = 0; r < 4; ++r)
        qkv[(size_t)(row0 + r) * QKVN + col] = f32_to_bf16(acc[mt][nt][r] + bias);
    }
  }
}

// Out GEMM (swapped): C[j][l] = WoT[j][c] * att[b*L+l][c] + bo[j], fp32 store
// to out[b][j][l] -- coalesced along l (MFMA C col = lane&15).
// 1D grid 2048 with XCD chunking: XCD k owns exactly b=k (256 blocks) ->
// per-XCD L2 read set = att[b] (2MB, written by attn on the same XCD) + woT
// (2MB) = exactly L2-sized. Final output stores are NON-TEMPORAL so the
// 16.8MB/XCD streaming write doesn't evict the resident read set.
__global__ __launch_bounds__(256) void out_gemm(const u16* __restrict__ woT,
                                                const u16* __restrict__ att,
                                                const float* __restrict__ bo,
                                                float* __restrict__ out) {
  __shared__ __align__(16) u16 As[BM * BK];
  __shared__ __align__(16) u16 Bs[BN * BK];
  int id = blockIdx.x;                      // 2048 blocks, %8==0
  int swz = (id & 7) * 256 + (id >> 3);     // bijective XCD chunking (T1)
  int b = swz >> 8;
  int rem = swz & 255;
  int m0 = (rem >> 4) * BM;                 // j-panel
  int n0 = (rem & 15) * BN;                 // l-tile
  const u16* gB = att + (size_t)b * L_ * D_;
  f32x4 acc[4][4];
  gemm_tile<D_>(woT, gB, m0, n0, As, Bs, acc);
  const int lane = threadIdx.x & 63, wave = threadIdx.x >> 6;
  const int wm = wave >> 1, wn = wave & 1;
  float* outb = out + (size_t)b * DO_ * L_;
#pragma unroll
  for (int mt = 0; mt < 4; ++mt) {
    int row0 = m0 + wm * 64 + mt * 16 + (lane >> 4) * 4;
#pragma unroll
    for (int r = 0; r < 4; ++r) {
      float bias = bo[row0 + r];
#pragma unroll
      for (int nt = 0; nt < 4; ++nt) {
        int col = n0 + wn * 64 + nt * 16 + (lane & 15);
        __builtin_nontemporal_store(acc[mt][nt][r] + bias,
                                    &outb[(size_t)(row0 + r) * L_ + col]);
      }
    }
  }
}

// ---------------------------------------------------------------------------
// Windowed attention, 2 rows per wave (round-5 verified). OOB window rows use
// k=v=0 and PARTICIPATE in softmax with score 0 (zero-pad semantics).
// 1024 blocks x 512 threads; XCD-chunked so XCD k handles batch b=k.
// ---------------------------------------------------------------------------
__global__ __launch_bounds__(512) void attn_kernel(const u16* __restrict__ qkv,
                                                   u16* __restrict__ att) {
  const int wave = threadIdx.x >> 6, lane = threadIdx.x & 63;
  int id = blockIdx.x;                      // 1024 blocks, %8==0
  int swz = (id & 7) * 128 + (id >> 3);     // bijective XCD chunking (T1)
  const int g = swz * 8 + wave;             // 8192 groups of 2 rows
  const int gr0 = g * 2;                    // first global row (even)
  const int l0 = gr0 & (L_ - 1);            // local l of row 0 (even)
  const int c0 = (lane >> 3) * 64 + (lane & 7) * 8;   // channel base, 8 per lane

  float q[2][8];
  load8(qkv + (size_t)gr0 * QKVN + c0, q[0]);
  load8(qkv + (size_t)(gr0 + 1) * QKVN + c0, q[1]);

  // k/v rows gr0-1 .. gr0+2  (j = 0..3)
  float kk[4][8], vv[4][8];
#pragma unroll
  for (int j = 0; j < 4; ++j) {
    bool valid = !(j == 0 && l0 == 0) && !(j == 3 && l0 == L_ - 2);
    if (valid) {
      const u16* base = qkv + (size_t)(gr0 - 1 + j) * QKVN;
      load8(base + 512 + c0, kk[j]);
      load8(base + 1024 + c0, vv[j]);
    } else {
#pragma unroll
      for (int t = 0; t < 8; ++t) { kk[j][t] = 0.f; vv[j][t] = 0.f; }
    }
  }

  // scores: row r window w uses k row j = r + w
  float s[2][3];
#pragma unroll
  for (int r = 0; r < 2; ++r)
#pragma unroll
    for (int w = 0; w < 3; ++w) {
      float a = 0.f;
#pragma unroll
      for (int t = 0; t < 8; ++t) a = fmaf(q[r][t], kk[r + w][t], a);
      s[r][w] = a;
    }
  // reduce over the 8 lanes of this head (butterfly; all lanes end with sum)
#pragma unroll
  for (int off = 1; off < 8; off <<= 1) {
#pragma unroll
    for (int r = 0; r < 2; ++r) {
      s[r][0] += __shfl_xor(s[r][0], off);
      s[r][1] += __shfl_xor(s[r][1], off);
      s[r][2] += __shfl_xor(s[r][2], off);
    }
  }

#pragma unroll
  for (int r = 0; r < 2; ++r) {
    float s0 = s[r][0] * 0.125f, s1 = s[r][1] * 0.125f, s2 = s[r][2] * 0.125f;
    float mx = fmaxf(s0, fmaxf(s1, s2));
    float e0 = __expf(s0 - mx), e1 = __expf(s1 - mx), e2 = __expf(s2 - mx);
    float inv = 1.f / (e0 + e1 + e2);
    float a0 = e0 * inv, a1 = e1 * inv, a2 = e2 * inv;

    u16 o16[8];
#pragma unroll
    for (int t = 0; t < 8; ++t) {
      float o = a0 * vv[r][t] + a1 * vv[r + 1][t] + a2 * vv[r + 2][t];
      o16[t] = f32_to_bf16(o);
    }
    uint4 pk;
    pk.x = (unsigned)o16[0] | ((unsigned)o16[1] << 16);
    pk.y = (unsigned)o16[2] | ((unsigned)o16[3] << 16);
    pk.z = (unsigned)o16[4] | ((unsigned)o16[5] << 16);
    pk.w = (unsigned)o16[6] | ((unsigned)o16[7] << 16);
    *reinterpret_cast<uint4*>(att + (size_t)(gr0 + r) * D_ + c0) = pk;
  }
}

// ---------------------------------------------------------------------------
extern "C" void kernel_launch(void* const* d_in, const int* in_sizes, int n_in,
                              void* d_out, int out_size, void* d_ws, size_t ws_size,
                              hipStream_t stream) {
  const float* x  = (const float*)d_in[0];
  const float* Wq = (const float*)d_in[1];
  const float* bq = (const float*)d_in[2];
  const float* Wk = (const float*)d_in[3];
  const float* bk = (const float*)d_in[4];
  const float* Wv = (const float*)d_in[5];
  const float* bv = (const float*)d_in[6];
  const float* Wo = (const float*)d_in[7];
  const float* bo = (const float*)d_in[8];
  float* out = (float*)d_out;

  char* ws = (char*)d_ws;
  // workspace layout (bytes)
  u16*   xb    = (u16*)(ws + 0);            //  16384x256  bf16  (8388608)
  u16*   wqkvT = (u16*)(ws + 8388608);      //  1536x256   bf16  (786432)
  u16*   woT   = (u16*)(ws + 9175040);      //  2048x512   bf16  (2097152)
  float* bqkv  = (float*)(ws + 11272192);   //  1536       f32   (6144)
  u16*   qkv   = (u16*)(ws + 11278336);     //  16384x1536 bf16  (50331648)
  u16*   att   = (u16*)(ws + 61609984);     //  16384x512  bf16  (16777216)
  // total ~78.4 MB

  // all transposes + bias in ONE launch (64x64 tiles, block (64,8))
  prep_all<<<PREP_NB, dim3(64, 8), 0, stream>>>(x, Wq, Wk, Wv, Wo, bq, bk, bv,
                                                xb, wqkvT, woT, bqkv);

  // QKV projection: [16384 x 1536] = xb [16384x256] * wqkvT^T
  qkv_gemm<<<(QKVN / BN) * ((B_ * L_) / BM), 256, 0, stream>>>(xb, wqkvT, bqkv, qkv);

  // windowed softmax attention -> att [16384x512] bf16 (2 rows/wave)
  attn_kernel<<<(B_ * L_) / 16, 512, 0, stream>>>(qkv, att);

  // output projection, transposed store: out[b][j][l]
  out_gemm<<<(L_ / BN) * (DO_ / BM) * B_, 256, 0, stream>>>(woT, att, bo, out);
}